// Round 1
// baseline (422.076 us; speedup 1.0000x reference)
//
#include <hip/hip_runtime.h>
#include <hip/hip_bf16.h>

typedef float floatx4 __attribute__((ext_vector_type(4)));
typedef short shortx8 __attribute__((ext_vector_type(8)));
typedef short shortx4 __attribute__((ext_vector_type(4)));

__device__ __forceinline__ float bf2f(short s) {
    union { unsigned u; float f; } cv;
    cv.u = ((unsigned)(unsigned short)s) << 16;
    return cv.f;
}
__device__ __forceinline__ short f2bf(float f) {
    union { float f; unsigned u; } cv; cv.f = f;
    unsigned r = (cv.u + 0x7fffu + ((cv.u >> 16) & 1u)) >> 16;
    return (short)r;
}

// ---------------- K0a: weight transpose + bf16 convert ----------------
// Wq,Wk,Wv -> wqkv_t[768][256]; Wo -> wo_t[256][256]  (row = output col n, col = k)
__global__ __launch_bounds__(256) void wtrans(const float* __restrict__ Wq,
                                              const float* __restrict__ Wk,
                                              const float* __restrict__ Wv,
                                              const float* __restrict__ Wo,
                                              short* __restrict__ wqkv_t,
                                              short* __restrict__ wo_t) {
    __shared__ float tile[32][33];
    int z = blockIdx.z;
    const float* src = (z == 0) ? Wq : (z == 1) ? Wk : (z == 2) ? Wv : Wo;
    int n0 = blockIdx.x * 32, k0 = blockIdx.y * 32;
    for (int p = threadIdx.y; p < 32; p += 8)
        tile[p][threadIdx.x] = src[(size_t)(k0 + p) * 256 + n0 + threadIdx.x];
    __syncthreads();
    for (int p = threadIdx.y; p < 32; p += 8) {
        int n = n0 + p, k = k0 + threadIdx.x;
        short b = f2bf(tile[threadIdx.x][p]);
        if (z < 3) wqkv_t[(size_t)(z * 256 + n) * 256 + k] = b;
        else       wo_t[(size_t)n * 256 + k] = b;
    }
}

// ---------------- K0b: CPB bias table + per-head scale ----------------
__device__ __forceinline__ float sgnlog(float x) {
    return copysignf(__log2f(fabsf(x) + 1.f) / 3.f, x);
}
__global__ __launch_bounds__(256) void bias_kernel(const float* __restrict__ ls,
                                                   const float* __restrict__ w1,
                                                   const float* __restrict__ b1,
                                                   const float* __restrict__ w2,
                                                   float* __restrict__ bias8,
                                                   float* __restrict__ scaleOut) {
    __shared__ float b225[225][8];
    int tid = threadIdx.x;
    if (tid < 8) scaleOut[tid] = expf(fminf(ls[tid], 4.6051701859880914f));
    if (tid < 225) {
        int dh = tid / 15 - 7, dw = tid % 15 - 7;
        float t0 = sgnlog(8.f * (float)dh / 7.f);
        float t1 = sgnlog(8.f * (float)dw / 7.f);
        float acc[8];
#pragma unroll
        for (int j = 0; j < 8; ++j) acc[j] = 0.f;
        for (int hsm = 0; hsm < 512; ++hsm) {
            float hid = fmaxf(0.f, t0 * w1[hsm] + t1 * w1[512 + hsm] + b1[hsm]);
#pragma unroll
            for (int j = 0; j < 8; ++j) acc[j] += hid * w2[hsm * 8 + j];
        }
#pragma unroll
        for (int j = 0; j < 8; ++j) b225[tid][j] = acc[j];
    }
    __syncthreads();
    for (int f = tid; f < 8 * 4096; f += 256) {
        int h = f >> 12, ij = f & 4095, i = ij >> 6, j = ij & 63;
        int dh = (i >> 3) - (j >> 3), dw = (i & 7) - (j & 7);
        int e = (dh + 7) * 15 + (dw + 7);
        float v = b225[e][h];
        bias8[f] = 16.f / (1.f + expf(-v));
    }
}

// token row -> source/dest pixel (roll by +4 both ways, same map fwd/bwd)
__device__ __forceinline__ int row2pix(int row) {
    int w = row >> 6, t = row & 63;
    int b = w >> 6, wi = (w >> 3) & 7, wj = w & 7;
    int hh = (wi * 8 + (t >> 3) + 4) & 63;
    int ww = (wj * 8 + (t & 7) + 4) & 63;
    return (b * 64 + hh) * 64 + ww;
}

// ---------------- K1: QKV projection GEMM (fused roll+window+convert A) ----------------
// C[65536][768] bf16 = windowed(x) @ [Wq|Wk|Wv] + [bq|bk|bv]
__global__ __launch_bounds__(256) void qkv_gemm(const float* __restrict__ x,
                                                const short* __restrict__ wt,
                                                const float* __restrict__ bq,
                                                const float* __restrict__ bk_,
                                                const float* __restrict__ bv,
                                                short* __restrict__ qkv) {
    __shared__ __align__(16) short As[128 * 56];
    __shared__ __align__(16) short Bs[64 * 56];
    int tid = threadIdx.x;
    int lane = tid & 63, wid = tid >> 6;
    int quad = lane >> 4, l15 = lane & 15;
    int bn = blockIdx.x, bm = blockIdx.y;

    int arow = tid >> 3, acol = (tid & 7) * 4;
    const float* abase[4];
#pragma unroll
    for (int p = 0; p < 4; ++p) {
        int row = bm * 128 + p * 32 + arow;
        abase[p] = x + (size_t)row2pix(row) * 256 + acol;
    }
    int brow = tid >> 2, bchunk = tid & 3;
    const short* bbase = wt + (size_t)(bn * 64 + brow) * 256 + bchunk * 8;

    int wm = (wid & 1) * 64, wn = (wid >> 1) * 32;
    floatx4 acc[4][2];
#pragma unroll
    for (int mt = 0; mt < 4; ++mt)
#pragma unroll
        for (int nt = 0; nt < 2; ++nt) acc[mt][nt] = (floatx4){0.f, 0.f, 0.f, 0.f};

    for (int kt = 0; kt < 8; ++kt) {
        float4 av[4];
#pragma unroll
        for (int p = 0; p < 4; ++p) av[p] = *(const float4*)(abase[p] + kt * 32);
        shortx8 bvv = *(const shortx8*)(bbase + kt * 32);
        __syncthreads();
#pragma unroll
        for (int p = 0; p < 4; ++p) {
            shortx4 s4 = {f2bf(av[p].x), f2bf(av[p].y), f2bf(av[p].z), f2bf(av[p].w)};
            *(shortx4*)&As[(p * 32 + arow) * 56 + acol] = s4;
        }
        *(shortx8*)&Bs[brow * 56 + bchunk * 8] = bvv;
        __syncthreads();
        shortx8 af[4], bfr[2];
#pragma unroll
        for (int mt = 0; mt < 4; ++mt)
            af[mt] = *(const shortx8*)&As[(wm + mt * 16 + l15) * 56 + quad * 8];
#pragma unroll
        for (int nt = 0; nt < 2; ++nt)
            bfr[nt] = *(const shortx8*)&Bs[(wn + nt * 16 + l15) * 56 + quad * 8];
#pragma unroll
        for (int mt = 0; mt < 4; ++mt)
#pragma unroll
            for (int nt = 0; nt < 2; ++nt)
                acc[mt][nt] = __builtin_amdgcn_mfma_f32_16x16x32_bf16(af[mt], bfr[nt], acc[mt][nt], 0, 0, 0);
    }
#pragma unroll
    for (int mt = 0; mt < 4; ++mt)
#pragma unroll
        for (int nt = 0; nt < 2; ++nt)
#pragma unroll
            for (int reg = 0; reg < 4; ++reg) {
                int row = bm * 128 + wm + mt * 16 + quad * 4 + reg;
                int col = bn * 64 + wn + nt * 16 + l15;
                float bias = (col < 256) ? bq[col] : (col < 512) ? bk_[col - 256] : bv[col - 512];
                qkv[(size_t)row * 768 + col] = f2bf(acc[mt][nt][reg] + bias);
            }
}

// ---------------- K3: per-window attention ----------------
__device__ __forceinline__ int regid(int t, int wi, int wj) {
    int a = (wi < 7) ? 0 : (((t >> 3) < 4) ? 1 : 2);
    int b = (wj < 7) ? 0 : (((t & 7) < 4) ? 1 : 2);
    return a * 3 + b;
}

__global__ __launch_bounds__(256) void attn_kernel(const short* __restrict__ qkv,
                                                   const float* __restrict__ bias8,
                                                   const float* __restrict__ scale,
                                                   short* __restrict__ aout) {
    // per-wave region: qn[64][56] + kn[64][56] shorts; P[64][88] aliases it
    __shared__ __align__(16) short lds[4 * 7168];
    int tid = threadIdx.x, lane = tid & 63, wid = tid >> 6;
    int quad = lane >> 4, l15 = lane & 15;
    int win = blockIdx.x;
    int wi = (win >> 3) & 7, wj = win & 7;
    bool need_mask = (wi == 7) || (wj == 7);
    short* qn = &lds[wid * 7168];
    short* kn = qn + 64 * 56;
    short* P = qn;

    for (int hi = 0; hi < 2; ++hi) {
        int h = wid + hi * 4;
        float sc = scale[h];
        const short* qp = qkv + (size_t)(win * 64 + lane) * 768 + h * 32;
        const short* kp = qp + 256;
        shortx8 qraw[4], kraw[4];
#pragma unroll
        for (int c2 = 0; c2 < 4; ++c2) {
            qraw[c2] = *(const shortx8*)(qp + c2 * 8);
            kraw[c2] = *(const shortx8*)(kp + c2 * 8);
        }
        float qs = 0.f, ks2 = 0.f;
#pragma unroll
        for (int c2 = 0; c2 < 4; ++c2)
#pragma unroll
            for (int j = 0; j < 8; ++j) {
                float f = bf2f(qraw[c2][j]); qs += f * f;
                float g = bf2f(kraw[c2][j]); ks2 += g * g;
            }
        float qr = sc / fmaxf(sqrtf(qs), 1e-12f);   // fold logit scale into qn
        float kr = 1.f / fmaxf(sqrtf(ks2), 1e-12f);
        __syncthreads();   // prev head's P reads done before overwrite
#pragma unroll
        for (int c2 = 0; c2 < 4; ++c2) {
            shortx8 oq, ok;
#pragma unroll
            for (int j = 0; j < 8; ++j) {
                oq[j] = f2bf(bf2f(qraw[c2][j]) * qr);
                ok[j] = f2bf(bf2f(kraw[c2][j]) * kr);
            }
            *(shortx8*)&qn[lane * 56 + c2 * 8] = oq;
            *(shortx8*)&kn[lane * 56 + c2 * 8] = ok;
        }
        __syncthreads();
        // S = qn @ kn^T  (M=64,N=64,K=32)
        shortx8 aq[4], bkf[4];
#pragma unroll
        for (int mt = 0; mt < 4; ++mt)
            aq[mt] = *(const shortx8*)&qn[(mt * 16 + l15) * 56 + quad * 8];
#pragma unroll
        for (int nt = 0; nt < 4; ++nt)
            bkf[nt] = *(const shortx8*)&kn[(nt * 16 + l15) * 56 + quad * 8];
        floatx4 S[4][4];
#pragma unroll
        for (int mt = 0; mt < 4; ++mt)
#pragma unroll
            for (int nt = 0; nt < 4; ++nt) {
                floatx4 z = {0.f, 0.f, 0.f, 0.f};
                S[mt][nt] = __builtin_amdgcn_mfma_f32_16x16x32_bf16(aq[mt], bkf[nt], z, 0, 0, 0);
            }
        // bias + mask + exp (fixed stable bound, no row-max pass) + row sums
        const float* bh = bias8 + (h << 12);
        float bound = sc + 16.5f;
        int jid[4];
        if (need_mask) {
#pragma unroll
            for (int nt = 0; nt < 4; ++nt) jid[nt] = regid(nt * 16 + l15, wi, wj);
        }
        float rs[4][4];
#pragma unroll
        for (int mt = 0; mt < 4; ++mt)
#pragma unroll
            for (int reg = 0; reg < 4; ++reg) {
                int i = mt * 16 + quad * 4 + reg;
                int iid = need_mask ? regid(i, wi, wj) : 0;
                float rowsum = 0.f;
#pragma unroll
                for (int nt = 0; nt < 4; ++nt) {
                    int j = nt * 16 + l15;
                    float v = S[mt][nt][reg] + bh[i * 64 + j];
                    if (need_mask && iid != jid[nt]) v -= 100.f;
                    float p = __expf(v - bound);
                    S[mt][nt][reg] = p;
                    rowsum += p;
                }
                rowsum += __shfl_xor(rowsum, 1, 64);
                rowsum += __shfl_xor(rowsum, 2, 64);
                rowsum += __shfl_xor(rowsum, 4, 64);
                rowsum += __shfl_xor(rowsum, 8, 64);
                rs[mt][reg] = 1.f / rowsum;
            }
        __syncthreads();  // all S-frag LDS reads done before P overwrites kn/qn
#pragma unroll
        for (int mt = 0; mt < 4; ++mt)
#pragma unroll
            for (int nt = 0; nt < 4; ++nt)
#pragma unroll
                for (int reg = 0; reg < 4; ++reg)
                    P[(mt * 16 + quad * 4 + reg) * 88 + nt * 16 + l15] = f2bf(S[mt][nt][reg]);
        __syncthreads();
        // O = P @ V  (M=64,N=32,K=64)
        floatx4 O[4][2];
#pragma unroll
        for (int mt = 0; mt < 4; ++mt)
#pragma unroll
            for (int nt = 0; nt < 2; ++nt) O[mt][nt] = (floatx4){0.f, 0.f, 0.f, 0.f};
#pragma unroll
        for (int ks = 0; ks < 2; ++ks) {
            shortx8 pa[4];
#pragma unroll
            for (int mt = 0; mt < 4; ++mt)
                pa[mt] = *(const shortx8*)&P[(mt * 16 + l15) * 88 + ks * 32 + quad * 8];
            shortx8 vb[2];
#pragma unroll
            for (int nt = 0; nt < 2; ++nt) {
                const short* vcol = qkv + (size_t)(win * 64 + ks * 32 + quad * 8) * 768 + 512 + h * 32 + nt * 16 + l15;
                shortx8 t;
#pragma unroll
                for (int jj = 0; jj < 8; ++jj) t[jj] = vcol[(size_t)jj * 768];
                vb[nt] = t;
            }
#pragma unroll
            for (int mt = 0; mt < 4; ++mt)
#pragma unroll
                for (int nt = 0; nt < 2; ++nt)
                    O[mt][nt] = __builtin_amdgcn_mfma_f32_16x16x32_bf16(pa[mt], vb[nt], O[mt][nt], 0, 0, 0);
        }
#pragma unroll
        for (int mt = 0; mt < 4; ++mt)
#pragma unroll
            for (int nt = 0; nt < 2; ++nt)
#pragma unroll
                for (int reg = 0; reg < 4; ++reg) {
                    int i = mt * 16 + quad * 4 + reg;
                    int d = nt * 16 + l15;
                    aout[(size_t)(win * 64 + i) * 256 + (h << 5) + d] =
                        f2bf(O[mt][nt][reg] * rs[mt][reg]);
                }
    }
}

// ---------------- K4: output projection + window-reverse + roll-back ----------------
__global__ __launch_bounds__(256) void oproj_gemm(const short* __restrict__ ao,
                                                  const short* __restrict__ wot,
                                                  const float* __restrict__ bo,
                                                  float* __restrict__ out) {
    __shared__ __align__(16) short As[128 * 56];
    __shared__ __align__(16) short Bs[64 * 56];
    int tid = threadIdx.x;
    int lane = tid & 63, wid = tid >> 6;
    int quad = lane >> 4, l15 = lane & 15;
    int bn = blockIdx.x, bm = blockIdx.y;

    int arow = tid >> 2, achunk = tid & 3;
    const short* abase0 = ao + (size_t)(bm * 128 + arow) * 256 + achunk * 8;
    const short* abase1 = abase0 + (size_t)64 * 256;
    int brow = tid >> 2, bchunk = tid & 3;
    const short* bbase = wot + (size_t)(bn * 64 + brow) * 256 + bchunk * 8;

    int wm = (wid & 1) * 64, wn = (wid >> 1) * 32;
    floatx4 acc[4][2];
#pragma unroll
    for (int mt = 0; mt < 4; ++mt)
#pragma unroll
        for (int nt = 0; nt < 2; ++nt) acc[mt][nt] = (floatx4){0.f, 0.f, 0.f, 0.f};

    for (int kt = 0; kt < 8; ++kt) {
        shortx8 a0 = *(const shortx8*)(abase0 + kt * 32);
        shortx8 a1 = *(const shortx8*)(abase1 + kt * 32);
        shortx8 bvv = *(const shortx8*)(bbase + kt * 32);
        __syncthreads();
        *(shortx8*)&As[arow * 56 + achunk * 8] = a0;
        *(shortx8*)&As[(64 + arow) * 56 + achunk * 8] = a1;
        *(shortx8*)&Bs[brow * 56 + bchunk * 8] = bvv;
        __syncthreads();
        shortx8 af[4], bfr[2];
#pragma unroll
        for (int mt = 0; mt < 4; ++mt)
            af[mt] = *(const shortx8*)&As[(wm + mt * 16 + l15) * 56 + quad * 8];
#pragma unroll
        for (int nt = 0; nt < 2; ++nt)
            bfr[nt] = *(const shortx8*)&Bs[(wn + nt * 16 + l15) * 56 + quad * 8];
#pragma unroll
        for (int mt = 0; mt < 4; ++mt)
#pragma unroll
            for (int nt = 0; nt < 2; ++nt)
                acc[mt][nt] = __builtin_amdgcn_mfma_f32_16x16x32_bf16(af[mt], bfr[nt], acc[mt][nt], 0, 0, 0);
    }
#pragma unroll
    for (int mt = 0; mt < 4; ++mt)
#pragma unroll
        for (int nt = 0; nt < 2; ++nt)
#pragma unroll
            for (int reg = 0; reg < 4; ++reg) {
                int row = bm * 128 + wm + mt * 16 + quad * 4 + reg;
                int col = bn * 64 + wn + nt * 16 + l15;
                out[(size_t)row2pix(row) * 256 + col] = acc[mt][nt][reg] + bo[col];
            }
}

// ---------------- launch ----------------
extern "C" void kernel_launch(void* const* d_in, const int* in_sizes, int n_in,
                              void* d_out, int out_size, void* d_ws, size_t ws_size,
                              hipStream_t stream) {
    const float* x  = (const float*)d_in[0];
    const float* Wq = (const float*)d_in[1];
    const float* bq = (const float*)d_in[2];
    const float* Wk = (const float*)d_in[3];
    const float* bk = (const float*)d_in[4];
    const float* Wv = (const float*)d_in[5];
    const float* bv = (const float*)d_in[6];
    const float* Wo = (const float*)d_in[7];
    const float* bo = (const float*)d_in[8];
    const float* ls = (const float*)d_in[9];
    const float* w1 = (const float*)d_in[10];
    const float* b1 = (const float*)d_in[11];
    const float* w2 = (const float*)d_in[12];

    char* ws = (char*)d_ws;
    short* wqkv_t = (short*)(ws + 0);           //   393,216 B
    short* wo_t   = (short*)(ws + 393216);      //   131,072 B
    float* bias8  = (float*)(ws + 524288);      //   131,072 B
    float* scale  = (float*)(ws + 655360);      //        32 B
    short* qkv    = (short*)(ws + 1048576);     // 100,663,296 B
    short* aout   = (short*)(ws + 101711872);   //  33,554,432 B
    float* out    = (float*)d_out;

    hipLaunchKernelGGL(wtrans, dim3(8, 8, 4), dim3(32, 8), 0, stream, Wq, Wk, Wv, Wo, wqkv_t, wo_t);
    hipLaunchKernelGGL(bias_kernel, dim3(1), dim3(256), 0, stream, ls, w1, b1, w2, bias8, scale);
    hipLaunchKernelGGL(qkv_gemm, dim3(12, 512), dim3(256), 0, stream, x, wqkv_t, bq, bk, bv, qkv);
    hipLaunchKernelGGL(attn_kernel, dim3(1024), dim3(256), 0, stream, qkv, bias8, scale, aout);
    hipLaunchKernelGGL(oproj_gemm, dim3(4, 512), dim3(256), 0, stream, aout, wo_t, bo, out);
}

// Round 2
// 320.177 us; speedup vs baseline: 1.3183x; 1.3183x over previous
//
#include <hip/hip_runtime.h>
#include <hip/hip_bf16.h>

typedef float floatx4 __attribute__((ext_vector_type(4)));
typedef short shortx8 __attribute__((ext_vector_type(8)));
typedef short shortx4 __attribute__((ext_vector_type(4)));

#define CFENCE() asm volatile("" ::: "memory")

__device__ __forceinline__ float bf2f(short s) {
    union { unsigned u; float f; } cv;
    cv.u = ((unsigned)(unsigned short)s) << 16;
    return cv.f;
}
__device__ __forceinline__ short f2bf(float f) {
    union { float f; unsigned u; } cv; cv.f = f;
    unsigned r = (cv.u + 0x7fffu + ((cv.u >> 16) & 1u)) >> 16;
    return (short)r;
}

// ---------------- K0a: weight transpose + bf16 convert ----------------
__global__ __launch_bounds__(256) void wtrans(const float* __restrict__ Wq,
                                              const float* __restrict__ Wk,
                                              const float* __restrict__ Wv,
                                              const float* __restrict__ Wo,
                                              short* __restrict__ wqkv_t,
                                              short* __restrict__ wo_t) {
    __shared__ float tile[32][33];
    int z = blockIdx.z;
    const float* src = (z == 0) ? Wq : (z == 1) ? Wk : (z == 2) ? Wv : Wo;
    int n0 = blockIdx.x * 32, k0 = blockIdx.y * 32;
    for (int p = threadIdx.y; p < 32; p += 8)
        tile[p][threadIdx.x] = src[(size_t)(k0 + p) * 256 + n0 + threadIdx.x];
    __syncthreads();
    for (int p = threadIdx.y; p < 32; p += 8) {
        int n = n0 + p, k = k0 + threadIdx.x;
        short b = f2bf(tile[threadIdx.x][p]);
        if (z < 3) wqkv_t[(size_t)(z * 256 + n) * 256 + k] = b;
        else       wo_t[(size_t)n * 256 + k] = b;
    }
}

// ---------------- K0b: CPB bias table + per-head scale ----------------
__device__ __forceinline__ float sgnlog(float x) {
    return copysignf(__log2f(fabsf(x) + 1.f) / 3.f, x);
}
__global__ __launch_bounds__(256) void bias_kernel(const float* __restrict__ ls,
                                                   const float* __restrict__ w1,
                                                   const float* __restrict__ b1,
                                                   const float* __restrict__ w2,
                                                   float* __restrict__ bias8,
                                                   float* __restrict__ scaleOut) {
    __shared__ float b225[225][8];
    int tid = threadIdx.x;
    if (tid < 8) scaleOut[tid] = expf(fminf(ls[tid], 4.6051701859880914f));
    if (tid < 225) {
        int dh = tid / 15 - 7, dw = tid % 15 - 7;
        float t0 = sgnlog(8.f * (float)dh / 7.f);
        float t1 = sgnlog(8.f * (float)dw / 7.f);
        float acc[8];
#pragma unroll
        for (int j = 0; j < 8; ++j) acc[j] = 0.f;
        for (int hsm = 0; hsm < 512; ++hsm) {
            float hid = fmaxf(0.f, t0 * w1[hsm] + t1 * w1[512 + hsm] + b1[hsm]);
#pragma unroll
            for (int j = 0; j < 8; ++j) acc[j] += hid * w2[hsm * 8 + j];
        }
#pragma unroll
        for (int j = 0; j < 8; ++j) b225[tid][j] = acc[j];
    }
    __syncthreads();
    for (int f = tid; f < 8 * 4096; f += 256) {
        int h = f >> 12, ij = f & 4095, i = ij >> 6, j = ij & 63;
        int dh = (i >> 3) - (j >> 3), dw = (i & 7) - (j & 7);
        int e = (dh + 7) * 15 + (dw + 7);
        float v = b225[e][h];
        bias8[f] = 16.f / (1.f + expf(-v));
    }
}

// token row -> pixel (roll by +4 both ways, same map fwd/bwd)
__device__ __forceinline__ int row2pix(int row) {
    int w = row >> 6, t = row & 63;
    int b = w >> 6, wi = (w >> 3) & 7, wj = w & 7;
    int hh = (wi * 8 + (t >> 3) + 4) & 63;
    int ww = (wj * 8 + (t & 7) + 4) & 63;
    return (b * 64 + hh) * 64 + ww;
}

// ---------------- K1: QKV projection, A-resident in LDS ----------------
// C[65536][768] bf16 = windowed(x) @ [Wq|Wk|Wv]^T_layout + bias
__global__ __launch_bounds__(256, 2) void qkv_gemm(const float* __restrict__ x,
                                                   const short* __restrict__ wt,
                                                   const float* __restrict__ bq,
                                                   const float* __restrict__ bk_,
                                                   const float* __restrict__ bv,
                                                   short* __restrict__ qkv) {
    __shared__ __align__(16) short As[128 * 264];  // 67584 B, stride 528B: 16B-group = r+chunk mod 8
    __shared__ __align__(16) short Bs[128 * 40];   // 10240 B, stride 80B: group = 5r+chunk mod 8
    int tid = threadIdx.x, lane = tid & 63, wid = tid >> 6;
    int quad = lane >> 4, l15 = lane & 15;
    int bm = blockIdx.x;

    // ---- stage A once: 128 rows x 256 k, fp32 gather -> bf16 LDS ----
    {
        int r = tid >> 1, half = tid & 1;
        const float* src = x + (size_t)row2pix(bm * 128 + r) * 256 + half * 128;
        short* dst = &As[r * 264 + half * 128];
#pragma unroll
        for (int g = 0; g < 4; ++g) {
            float4 v[8];
#pragma unroll
            for (int j = 0; j < 8; ++j) v[j] = *(const float4*)(src + g * 32 + j * 4);
#pragma unroll
            for (int j = 0; j < 4; ++j) {
                shortx8 s;
#pragma unroll
                for (int q2 = 0; q2 < 2; ++q2) {
                    float4 f = v[j * 2 + q2];
                    s[q2 * 4 + 0] = f2bf(f.x); s[q2 * 4 + 1] = f2bf(f.y);
                    s[q2 * 4 + 2] = f2bf(f.z); s[q2 * 4 + 3] = f2bf(f.w);
                }
                *(shortx8*)(dst + g * 32 + j * 8) = s;
            }
        }
    }

    int br = tid >> 1, bc = tid & 1;
    shortx8 pf0, pf1;
    {
        const short* p = wt + (size_t)br * 256 + bc * 16;
        pf0 = *(const shortx8*)p; pf1 = *(const shortx8*)(p + 8);
    }
    int wm = (wid & 1) * 64, wn = (wid >> 1) * 64;

    for (int t = 0; t < 6; ++t) {
        floatx4 acc[4][4];
#pragma unroll
        for (int mt = 0; mt < 4; ++mt)
#pragma unroll
            for (int nt = 0; nt < 4; ++nt) acc[mt][nt] = (floatx4){0.f, 0.f, 0.f, 0.f};
        for (int kt = 0; kt < 8; ++kt) {
            __syncthreads();
            *(shortx8*)&Bs[br * 40 + bc * 16] = pf0;
            *(shortx8*)&Bs[br * 40 + bc * 16 + 8] = pf1;
            __syncthreads();
            // prefetch next B k-slice while computing this one
            int nt_ = t, nkt = kt + 1;
            if (nkt == 8) { nt_ = t + 1; nkt = 0; }
            if (nt_ < 6) {
                const short* p = wt + (size_t)(nt_ * 128 + br) * 256 + nkt * 32 + bc * 16;
                pf0 = *(const shortx8*)p; pf1 = *(const shortx8*)(p + 8);
            }
            shortx8 af[4], bfr[4];
#pragma unroll
            for (int mt = 0; mt < 4; ++mt)
                af[mt] = *(const shortx8*)&As[(wm + mt * 16 + l15) * 264 + kt * 32 + quad * 8];
#pragma unroll
            for (int nt = 0; nt < 4; ++nt)
                bfr[nt] = *(const shortx8*)&Bs[(wn + nt * 16 + l15) * 40 + quad * 8];
#pragma unroll
            for (int mt = 0; mt < 4; ++mt)
#pragma unroll
                for (int nt = 0; nt < 4; ++nt)
                    acc[mt][nt] = __builtin_amdgcn_mfma_f32_16x16x32_bf16(af[mt], bfr[nt], acc[mt][nt], 0, 0, 0);
        }
        float biasv[4];
#pragma unroll
        for (int nt = 0; nt < 4; ++nt) {
            int col = t * 128 + wn + nt * 16 + l15;
            biasv[nt] = (col < 256) ? bq[col] : (col < 512) ? bk_[col - 256] : bv[col - 512];
        }
#pragma unroll
        for (int mt = 0; mt < 4; ++mt)
#pragma unroll
            for (int nt = 0; nt < 4; ++nt)
#pragma unroll
                for (int reg = 0; reg < 4; ++reg) {
                    int row = bm * 128 + wm + mt * 16 + quad * 4 + reg;
                    int col = t * 128 + wn + nt * 16 + l15;
                    qkv[(size_t)row * 768 + col] = f2bf(acc[mt][nt][reg] + biasv[nt]);
                }
    }
}

// ---------------- K3: per-window attention (wave-private LDS, no barriers) ----------------
__device__ __forceinline__ int regid(int t, int wi, int wj) {
    int a = (wi < 7) ? 0 : (((t >> 3) < 4) ? 1 : 2);
    int b = (wj < 7) ? 0 : (((t & 7) < 4) ? 1 : 2);
    return a * 3 + b;
}

__global__ __launch_bounds__(256, 2) void attn_kernel(const short* __restrict__ qkv,
                                                      const float* __restrict__ bias8,
                                                      const float* __restrict__ scale,
                                                      short* __restrict__ aout) {
    // per-wave region 8192 shorts: qn[64][56] | kn[64][56] ; later P[64][88] (aliases qn+)
    // and vt[32][72] at offset 5632 (aliases tail of kn)
    __shared__ __align__(16) short lds[4 * 8192];
    int tid = threadIdx.x, lane = tid & 63, wid = tid >> 6;
    int quad = lane >> 4, l15 = lane & 15;
    int win = blockIdx.x;
    int wi = (win >> 3) & 7, wj = win & 7;
    bool need_mask = (wi == 7) || (wj == 7);
    short* qn = &lds[wid * 8192];
    short* kn = qn + 3584;
    short* P = qn;
    short* vt = qn + 5632;

    for (int hi = 0; hi < 2; ++hi) {
        int h = wid + hi * 4;
        float sc = scale[h];
        const short* qp = qkv + (size_t)(win * 64 + lane) * 768 + h * 32;
        shortx8 qraw[4], kraw[4], vraw[4];
#pragma unroll
        for (int c2 = 0; c2 < 4; ++c2) {
            qraw[c2] = *(const shortx8*)(qp + c2 * 8);
            kraw[c2] = *(const shortx8*)(qp + 256 + c2 * 8);
            vraw[c2] = *(const shortx8*)(qp + 512 + c2 * 8);
        }
        float qs = 0.f, ks2 = 0.f;
#pragma unroll
        for (int c2 = 0; c2 < 4; ++c2)
#pragma unroll
            for (int j = 0; j < 8; ++j) {
                float f = bf2f(qraw[c2][j]); qs += f * f;
                float g = bf2f(kraw[c2][j]); ks2 += g * g;
            }
        float qr = sc / fmaxf(sqrtf(qs), 1e-12f);
        float kr = 1.f / fmaxf(sqrtf(ks2), 1e-12f);
        CFENCE();  // prior iter's P/vt reads ordered before these writes (DS in-order per wave)
#pragma unroll
        for (int c2 = 0; c2 < 4; ++c2) {
            shortx8 oq, ok;
#pragma unroll
            for (int j = 0; j < 8; ++j) {
                oq[j] = f2bf(bf2f(qraw[c2][j]) * qr);
                ok[j] = f2bf(bf2f(kraw[c2][j]) * kr);
            }
            *(shortx8*)&qn[lane * 56 + c2 * 8] = oq;
            *(shortx8*)&kn[lane * 56 + c2 * 8] = ok;
        }
        CFENCE();
        shortx8 aq[4], bkf[4];
#pragma unroll
        for (int mt = 0; mt < 4; ++mt)
            aq[mt] = *(const shortx8*)&qn[(mt * 16 + l15) * 56 + quad * 8];
#pragma unroll
        for (int nt = 0; nt < 4; ++nt)
            bkf[nt] = *(const shortx8*)&kn[(nt * 16 + l15) * 56 + quad * 8];
        floatx4 S[4][4];
#pragma unroll
        for (int mt = 0; mt < 4; ++mt)
#pragma unroll
            for (int nt = 0; nt < 4; ++nt) {
                floatx4 z = {0.f, 0.f, 0.f, 0.f};
                S[mt][nt] = __builtin_amdgcn_mfma_f32_16x16x32_bf16(aq[mt], bkf[nt], z, 0, 0, 0);
            }
        const float* bh = bias8 + (h << 12);
        float bound = sc + 16.5f;
        int jid[4];
        if (need_mask) {
#pragma unroll
            for (int nt = 0; nt < 4; ++nt) jid[nt] = regid(nt * 16 + l15, wi, wj);
        }
        float rs[4][4];
#pragma unroll
        for (int mt = 0; mt < 4; ++mt)
#pragma unroll
            for (int reg = 0; reg < 4; ++reg) {
                int i = mt * 16 + quad * 4 + reg;
                int iid = need_mask ? regid(i, wi, wj) : 0;
                float rowsum = 0.f;
#pragma unroll
                for (int nt = 0; nt < 4; ++nt) {
                    int j = nt * 16 + l15;
                    float v = S[mt][nt][reg] + bh[i * 64 + j];
                    if (need_mask && iid != jid[nt]) v -= 100.f;
                    float p = __expf(v - bound);
                    S[mt][nt][reg] = p;
                    rowsum += p;
                }
                rowsum += __shfl_xor(rowsum, 1, 64);
                rowsum += __shfl_xor(rowsum, 2, 64);
                rowsum += __shfl_xor(rowsum, 4, 64);
                rowsum += __shfl_xor(rowsum, 8, 64);
                rs[mt][reg] = 1.f / rowsum;
            }
        CFENCE();  // qn/kn frag reads ordered before P/vt writes
#pragma unroll
        for (int mt = 0; mt < 4; ++mt)
#pragma unroll
            for (int nt = 0; nt < 4; ++nt)
#pragma unroll
                for (int reg = 0; reg < 4; ++reg)
                    P[(mt * 16 + quad * 4 + reg) * 88 + nt * 16 + l15] = f2bf(S[mt][nt][reg]);
        // V transpose into vt[d][tok]
#pragma unroll
        for (int c2 = 0; c2 < 4; ++c2)
#pragma unroll
            for (int j = 0; j < 8; ++j)
                vt[(c2 * 8 + j) * 72 + lane] = vraw[c2][j];
        CFENCE();
        floatx4 O[4][2];
#pragma unroll
        for (int mt = 0; mt < 4; ++mt)
#pragma unroll
            for (int nt = 0; nt < 2; ++nt) O[mt][nt] = (floatx4){0.f, 0.f, 0.f, 0.f};
#pragma unroll
        for (int ks = 0; ks < 2; ++ks) {
            shortx8 pa[4], vb[2];
#pragma unroll
            for (int mt = 0; mt < 4; ++mt)
                pa[mt] = *(const shortx8*)&P[(mt * 16 + l15) * 88 + ks * 32 + quad * 8];
#pragma unroll
            for (int nt = 0; nt < 2; ++nt)
                vb[nt] = *(const shortx8*)&vt[(nt * 16 + l15) * 72 + ks * 32 + quad * 8];
#pragma unroll
            for (int mt = 0; mt < 4; ++mt)
#pragma unroll
                for (int nt = 0; nt < 2; ++nt)
                    O[mt][nt] = __builtin_amdgcn_mfma_f32_16x16x32_bf16(pa[mt], vb[nt], O[mt][nt], 0, 0, 0);
        }
#pragma unroll
        for (int mt = 0; mt < 4; ++mt)
#pragma unroll
            for (int nt = 0; nt < 2; ++nt)
#pragma unroll
                for (int reg = 0; reg < 4; ++reg) {
                    int i = mt * 16 + quad * 4 + reg;
                    int d = nt * 16 + l15;
                    aout[(size_t)(win * 64 + i) * 256 + (h << 5) + d] =
                        f2bf(O[mt][nt][reg] * rs[mt][reg]);
                }
    }
}

// ---------------- K4: output projection, A-resident ----------------
__global__ __launch_bounds__(256, 2) void oproj_gemm(const short* __restrict__ ao,
                                                     const short* __restrict__ wot,
                                                     const float* __restrict__ bo,
                                                     float* __restrict__ out) {
    __shared__ __align__(16) short As[128 * 264];
    __shared__ __align__(16) short Bs[128 * 40];
    int tid = threadIdx.x, lane = tid & 63, wid = tid >> 6;
    int quad = lane >> 4, l15 = lane & 15;
    int bm = blockIdx.x;

    {
        int r = tid >> 1, half = tid & 1;
        const short* src = ao + (size_t)(bm * 128 + r) * 256 + half * 128;
        short* dst = &As[r * 264 + half * 128];
#pragma unroll
        for (int g = 0; g < 2; ++g) {
            shortx8 v[8];
#pragma unroll
            for (int j = 0; j < 8; ++j) v[j] = *(const shortx8*)(src + g * 64 + j * 8);
#pragma unroll
            for (int j = 0; j < 8; ++j) *(shortx8*)(dst + g * 64 + j * 8) = v[j];
        }
    }

    int br = tid >> 1, bc = tid & 1;
    shortx8 pf0, pf1;
    {
        const short* p = wot + (size_t)br * 256 + bc * 16;
        pf0 = *(const shortx8*)p; pf1 = *(const shortx8*)(p + 8);
    }
    int wm = (wid & 1) * 64, wn = (wid >> 1) * 64;

    for (int t = 0; t < 2; ++t) {
        floatx4 acc[4][4];
#pragma unroll
        for (int mt = 0; mt < 4; ++mt)
#pragma unroll
            for (int nt = 0; nt < 4; ++nt) acc[mt][nt] = (floatx4){0.f, 0.f, 0.f, 0.f};
        for (int kt = 0; kt < 8; ++kt) {
            __syncthreads();
            *(shortx8*)&Bs[br * 40 + bc * 16] = pf0;
            *(shortx8*)&Bs[br * 40 + bc * 16 + 8] = pf1;
            __syncthreads();
            int nt_ = t, nkt = kt + 1;
            if (nkt == 8) { nt_ = t + 1; nkt = 0; }
            if (nt_ < 2) {
                const short* p = wot + (size_t)(nt_ * 128 + br) * 256 + nkt * 32 + bc * 16;
                pf0 = *(const shortx8*)p; pf1 = *(const shortx8*)(p + 8);
            }
            shortx8 af[4], bfr[4];
#pragma unroll
            for (int mt = 0; mt < 4; ++mt)
                af[mt] = *(const shortx8*)&As[(wm + mt * 16 + l15) * 264 + kt * 32 + quad * 8];
#pragma unroll
            for (int nt = 0; nt < 4; ++nt)
                bfr[nt] = *(const shortx8*)&Bs[(wn + nt * 16 + l15) * 40 + quad * 8];
#pragma unroll
            for (int mt = 0; mt < 4; ++mt)
#pragma unroll
                for (int nt = 0; nt < 4; ++nt)
                    acc[mt][nt] = __builtin_amdgcn_mfma_f32_16x16x32_bf16(af[mt], bfr[nt], acc[mt][nt], 0, 0, 0);
        }
        float biasv[4];
#pragma unroll
        for (int nt = 0; nt < 4; ++nt) biasv[nt] = bo[t * 128 + wn + nt * 16 + l15];
#pragma unroll
        for (int mt = 0; mt < 4; ++mt)
#pragma unroll
            for (int nt = 0; nt < 4; ++nt)
#pragma unroll
                for (int reg = 0; reg < 4; ++reg) {
                    int row = bm * 128 + wm + mt * 16 + quad * 4 + reg;
                    int col = t * 128 + wn + nt * 16 + l15;
                    out[(size_t)row2pix(row) * 256 + col] = acc[mt][nt][reg] + biasv[nt];
                }
    }
}

// ---------------- launch ----------------
extern "C" void kernel_launch(void* const* d_in, const int* in_sizes, int n_in,
                              void* d_out, int out_size, void* d_ws, size_t ws_size,
                              hipStream_t stream) {
    const float* x  = (const float*)d_in[0];
    const float* Wq = (const float*)d_in[1];
    const float* bq = (const float*)d_in[2];
    const float* Wk = (const float*)d_in[3];
    const float* bk = (const float*)d_in[4];
    const float* Wv = (const float*)d_in[5];
    const float* bv = (const float*)d_in[6];
    const float* Wo = (const float*)d_in[7];
    const float* bo = (const float*)d_in[8];
    const float* ls = (const float*)d_in[9];
    const float* w1 = (const float*)d_in[10];
    const float* b1 = (const float*)d_in[11];
    const float* w2 = (const float*)d_in[12];

    char* ws = (char*)d_ws;
    short* wqkv_t = (short*)(ws + 0);
    short* wo_t   = (short*)(ws + 393216);
    float* bias8  = (float*)(ws + 524288);
    float* scale  = (float*)(ws + 655360);
    short* qkv    = (short*)(ws + 1048576);
    short* aout   = (short*)(ws + 101711872);
    float* out    = (float*)d_out;

    hipLaunchKernelGGL(wtrans, dim3(8, 8, 4), dim3(32, 8), 0, stream, Wq, Wk, Wv, Wo, wqkv_t, wo_t);
    hipLaunchKernelGGL(bias_kernel, dim3(1), dim3(256), 0, stream, ls, w1, b1, w2, bias8, scale);
    hipLaunchKernelGGL(qkv_gemm, dim3(512), dim3(256), 0, stream, x, wqkv_t, bq, bk, bv, qkv);
    hipLaunchKernelGGL(attn_kernel, dim3(1024), dim3(256), 0, stream, qkv, bias8, scale, aout);
    hipLaunchKernelGGL(oproj_gemm, dim3(512), dim3(256), 0, stream, aout, wo_t, bo, out);
}

// Round 3
// 248.301 us; speedup vs baseline: 1.6999x; 1.2895x over previous
//
#include <hip/hip_runtime.h>
#include <hip/hip_bf16.h>

typedef float floatx4 __attribute__((ext_vector_type(4)));
typedef short shortx8 __attribute__((ext_vector_type(8)));
typedef short shortx4 __attribute__((ext_vector_type(4)));

#define CFENCE() asm volatile("" ::: "memory")

__device__ __forceinline__ float bf2f(short s) {
    union { unsigned u; float f; } cv;
    cv.u = ((unsigned)(unsigned short)s) << 16;
    return cv.f;
}
__device__ __forceinline__ short f2bf(float f) {
    union { float f; unsigned u; } cv; cv.f = f;
    unsigned r = (cv.u + 0x7fffu + ((cv.u >> 16) & 1u)) >> 16;
    return (short)r;
}

// ---------------- K0a: weight transpose + bf16 convert ----------------
__global__ __launch_bounds__(256) void wtrans(const float* __restrict__ Wq,
                                              const float* __restrict__ Wk,
                                              const float* __restrict__ Wv,
                                              const float* __restrict__ Wo,
                                              short* __restrict__ wqkv_t,
                                              short* __restrict__ wo_t) {
    __shared__ float tile[32][33];
    int z = blockIdx.z;
    const float* src = (z == 0) ? Wq : (z == 1) ? Wk : (z == 2) ? Wv : Wo;
    int n0 = blockIdx.x * 32, k0 = blockIdx.y * 32;
    for (int p = threadIdx.y; p < 32; p += 8)
        tile[p][threadIdx.x] = src[(size_t)(k0 + p) * 256 + n0 + threadIdx.x];
    __syncthreads();
    for (int p = threadIdx.y; p < 32; p += 8) {
        int n = n0 + p, k = k0 + threadIdx.x;
        short b = f2bf(tile[threadIdx.x][p]);
        if (z < 3) wqkv_t[(size_t)(z * 256 + n) * 256 + k] = b;
        else       wo_t[(size_t)n * 256 + k] = b;
    }
}

// ---------------- K0b: CPB MLP, one block per table entry ----------------
__device__ __forceinline__ float sgnlog(float x) {
    return copysignf(__log2f(fabsf(x) + 1.f) / 3.f, x);
}
__global__ __launch_bounds__(256) void bias_mlp(const float* __restrict__ ls,
                                                const float* __restrict__ w1,
                                                const float* __restrict__ b1,
                                                const float* __restrict__ w2,
                                                float* __restrict__ b225g,
                                                float* __restrict__ scaleOut) {
    int e = blockIdx.x;  // 0..224
    int tid = threadIdx.x, lane = tid & 63, wid = tid >> 6;
    if (e == 0 && tid < 8) scaleOut[tid] = expf(fminf(ls[tid], 4.6051701859880914f));
    int dh = e / 15 - 7, dw = e % 15 - 7;
    float t0 = sgnlog(8.f * (float)dh / 7.f);
    float t1 = sgnlog(8.f * (float)dw / 7.f);
    float acc[8];
#pragma unroll
    for (int j = 0; j < 8; ++j) acc[j] = 0.f;
#pragma unroll
    for (int s = 0; s < 2; ++s) {
        int hsm = tid + s * 256;
        float hid = fmaxf(0.f, t0 * w1[hsm] + t1 * w1[512 + hsm] + b1[hsm]);
#pragma unroll
        for (int j = 0; j < 8; ++j) acc[j] += hid * w2[hsm * 8 + j];
    }
#pragma unroll
    for (int off = 1; off < 64; off <<= 1)
#pragma unroll
        for (int j = 0; j < 8; ++j) acc[j] += __shfl_xor(acc[j], off, 64);
    __shared__ float red[4][8];
    if (lane == 0)
#pragma unroll
        for (int j = 0; j < 8; ++j) red[wid][j] = acc[j];
    __syncthreads();
    if (tid < 8)
        b225g[e * 8 + tid] = red[0][tid] + red[1][tid] + red[2][tid] + red[3][tid];
}

// ---------------- K0c: expand to per-head 64x64 bias with 16*sigmoid ----------------
__global__ __launch_bounds__(256) void bias_expand(const float* __restrict__ b225g,
                                                   float* __restrict__ bias8) {
    int f = blockIdx.x * 256 + threadIdx.x;  // 0 .. 32767
    int h = f >> 12, ij = f & 4095, i = ij >> 6, j = ij & 63;
    int dh = (i >> 3) - (j >> 3), dw = (i & 7) - (j & 7);
    int e = (dh + 7) * 15 + (dw + 7);
    float v = b225g[e * 8 + h];
    bias8[f] = 16.f / (1.f + expf(-v));
}

// token row -> pixel (roll by +4 both ways, same map fwd/bwd)
__device__ __forceinline__ int row2pix(int row) {
    int w = row >> 6, t = row & 63;
    int b = w >> 6, wi = (w >> 3) & 7, wj = w & 7;
    int hh = (wi * 8 + (t >> 3) + 4) & 63;
    int ww = (wj * 8 + (t & 7) + 4) & 63;
    return (b * 64 + hh) * 64 + ww;
}

// ---------------- K1: QKV projection, A-resident in LDS ----------------
__global__ __launch_bounds__(256, 2) void qkv_gemm(const float* __restrict__ x,
                                                   const short* __restrict__ wt,
                                                   const float* __restrict__ bq,
                                                   const float* __restrict__ bk_,
                                                   const float* __restrict__ bv,
                                                   short* __restrict__ qkv) {
    __shared__ __align__(16) short As[128 * 264];
    __shared__ __align__(16) short Bs[128 * 40];
    int tid = threadIdx.x, lane = tid & 63, wid = tid >> 6;
    int quad = lane >> 4, l15 = lane & 15;
    int bm = blockIdx.x;

    {
        int r = tid >> 1, half = tid & 1;
        const float* src = x + (size_t)row2pix(bm * 128 + r) * 256 + half * 128;
        short* dst = &As[r * 264 + half * 128];
#pragma unroll
        for (int g = 0; g < 4; ++g) {
            float4 v[8];
#pragma unroll
            for (int j = 0; j < 8; ++j) v[j] = *(const float4*)(src + g * 32 + j * 4);
#pragma unroll
            for (int j = 0; j < 4; ++j) {
                shortx8 s;
#pragma unroll
                for (int q2 = 0; q2 < 2; ++q2) {
                    float4 f = v[j * 2 + q2];
                    s[q2 * 4 + 0] = f2bf(f.x); s[q2 * 4 + 1] = f2bf(f.y);
                    s[q2 * 4 + 2] = f2bf(f.z); s[q2 * 4 + 3] = f2bf(f.w);
                }
                *(shortx8*)(dst + g * 32 + j * 8) = s;
            }
        }
    }

    int br = tid >> 1, bc = tid & 1;
    shortx8 pf0, pf1;
    {
        const short* p = wt + (size_t)br * 256 + bc * 16;
        pf0 = *(const shortx8*)p; pf1 = *(const shortx8*)(p + 8);
    }
    int wm = (wid & 1) * 64, wn = (wid >> 1) * 64;

    for (int t = 0; t < 6; ++t) {
        floatx4 acc[4][4];
#pragma unroll
        for (int mt = 0; mt < 4; ++mt)
#pragma unroll
            for (int nt = 0; nt < 4; ++nt) acc[mt][nt] = (floatx4){0.f, 0.f, 0.f, 0.f};
        for (int kt = 0; kt < 8; ++kt) {
            __syncthreads();
            *(shortx8*)&Bs[br * 40 + bc * 16] = pf0;
            *(shortx8*)&Bs[br * 40 + bc * 16 + 8] = pf1;
            __syncthreads();
            int nt_ = t, nkt = kt + 1;
            if (nkt == 8) { nt_ = t + 1; nkt = 0; }
            if (nt_ < 6) {
                const short* p = wt + (size_t)(nt_ * 128 + br) * 256 + nkt * 32 + bc * 16;
                pf0 = *(const shortx8*)p; pf1 = *(const shortx8*)(p + 8);
            }
            shortx8 af[4], bfr[4];
#pragma unroll
            for (int mt = 0; mt < 4; ++mt)
                af[mt] = *(const shortx8*)&As[(wm + mt * 16 + l15) * 264 + kt * 32 + quad * 8];
#pragma unroll
            for (int nt = 0; nt < 4; ++nt)
                bfr[nt] = *(const shortx8*)&Bs[(wn + nt * 16 + l15) * 40 + quad * 8];
#pragma unroll
            for (int mt = 0; mt < 4; ++mt)
#pragma unroll
                for (int nt = 0; nt < 4; ++nt)
                    acc[mt][nt] = __builtin_amdgcn_mfma_f32_16x16x32_bf16(af[mt], bfr[nt], acc[mt][nt], 0, 0, 0);
        }
        float biasv[4];
#pragma unroll
        for (int nt = 0; nt < 4; ++nt) {
            int col = t * 128 + wn + nt * 16 + l15;
            biasv[nt] = (col < 256) ? bq[col] : (col < 512) ? bk_[col - 256] : bv[col - 512];
        }
#pragma unroll
        for (int mt = 0; mt < 4; ++mt)
#pragma unroll
            for (int nt = 0; nt < 4; ++nt)
#pragma unroll
                for (int reg = 0; reg < 4; ++reg) {
                    int row = bm * 128 + wm + mt * 16 + quad * 4 + reg;
                    int col = t * 128 + wn + nt * 16 + l15;
                    qkv[(size_t)row * 768 + col] = f2bf(acc[mt][nt][reg] + biasv[nt]);
                }
    }
}

// ---------------- K3: per-window attention (wave-private LDS, no barriers) ----------------
__device__ __forceinline__ int regid(int t, int wi, int wj) {
    int a = (wi < 7) ? 0 : (((t >> 3) < 4) ? 1 : 2);
    int b = (wj < 7) ? 0 : (((t & 7) < 4) ? 1 : 2);
    return a * 3 + b;
}

__global__ __launch_bounds__(256, 2) void attn_kernel(const short* __restrict__ qkv,
                                                      const float* __restrict__ bias8,
                                                      const float* __restrict__ scale,
                                                      short* __restrict__ aout) {
    __shared__ __align__(16) short lds[4 * 8192];
    int tid = threadIdx.x, lane = tid & 63, wid = tid >> 6;
    int quad = lane >> 4, l15 = lane & 15;
    int win = blockIdx.x;
    int wi = (win >> 3) & 7, wj = win & 7;
    bool need_mask = (wi == 7) || (wj == 7);
    short* qn = &lds[wid * 8192];
    short* kn = qn + 3584;
    short* P = qn;
    short* vt = qn + 5632;

    for (int hi = 0; hi < 2; ++hi) {
        int h = wid + hi * 4;
        float sc = scale[h];
        const short* qp = qkv + (size_t)(win * 64 + lane) * 768 + h * 32;
        shortx8 qraw[4], kraw[4], vraw[4];
#pragma unroll
        for (int c2 = 0; c2 < 4; ++c2) {
            qraw[c2] = *(const shortx8*)(qp + c2 * 8);
            kraw[c2] = *(const shortx8*)(qp + 256 + c2 * 8);
            vraw[c2] = *(const shortx8*)(qp + 512 + c2 * 8);
        }
        float qs = 0.f, ks2 = 0.f;
#pragma unroll
        for (int c2 = 0; c2 < 4; ++c2)
#pragma unroll
            for (int j = 0; j < 8; ++j) {
                float f = bf2f(qraw[c2][j]); qs += f * f;
                float g = bf2f(kraw[c2][j]); ks2 += g * g;
            }
        float qr = sc / fmaxf(sqrtf(qs), 1e-12f);
        float kr = 1.f / fmaxf(sqrtf(ks2), 1e-12f);
        CFENCE();
#pragma unroll
        for (int c2 = 0; c2 < 4; ++c2) {
            shortx8 oq, ok;
#pragma unroll
            for (int j = 0; j < 8; ++j) {
                oq[j] = f2bf(bf2f(qraw[c2][j]) * qr);
                ok[j] = f2bf(bf2f(kraw[c2][j]) * kr);
            }
            *(shortx8*)&qn[lane * 56 + c2 * 8] = oq;
            *(shortx8*)&kn[lane * 56 + c2 * 8] = ok;
        }
        CFENCE();
        shortx8 aq[4], bkf[4];
#pragma unroll
        for (int mt = 0; mt < 4; ++mt)
            aq[mt] = *(const shortx8*)&qn[(mt * 16 + l15) * 56 + quad * 8];
#pragma unroll
        for (int nt = 0; nt < 4; ++nt)
            bkf[nt] = *(const shortx8*)&kn[(nt * 16 + l15) * 56 + quad * 8];
        floatx4 S[4][4];
#pragma unroll
        for (int mt = 0; mt < 4; ++mt)
#pragma unroll
            for (int nt = 0; nt < 4; ++nt) {
                floatx4 z = {0.f, 0.f, 0.f, 0.f};
                S[mt][nt] = __builtin_amdgcn_mfma_f32_16x16x32_bf16(aq[mt], bkf[nt], z, 0, 0, 0);
            }
        const float* bh = bias8 + (h << 12);
        float bound = sc + 16.5f;
        int jid[4];
        if (need_mask) {
#pragma unroll
            for (int nt = 0; nt < 4; ++nt) jid[nt] = regid(nt * 16 + l15, wi, wj);
        }
        float rs[4][4];
#pragma unroll
        for (int mt = 0; mt < 4; ++mt)
#pragma unroll
            for (int reg = 0; reg < 4; ++reg) {
                int i = mt * 16 + quad * 4 + reg;
                int iid = need_mask ? regid(i, wi, wj) : 0;
                float rowsum = 0.f;
#pragma unroll
                for (int nt = 0; nt < 4; ++nt) {
                    int j = nt * 16 + l15;
                    float v = S[mt][nt][reg] + bh[i * 64 + j];
                    if (need_mask && iid != jid[nt]) v -= 100.f;
                    float p = __expf(v - bound);
                    S[mt][nt][reg] = p;
                    rowsum += p;
                }
                rowsum += __shfl_xor(rowsum, 1, 64);
                rowsum += __shfl_xor(rowsum, 2, 64);
                rowsum += __shfl_xor(rowsum, 4, 64);
                rowsum += __shfl_xor(rowsum, 8, 64);
                rs[mt][reg] = 1.f / rowsum;
            }
        CFENCE();
#pragma unroll
        for (int mt = 0; mt < 4; ++mt)
#pragma unroll
            for (int nt = 0; nt < 4; ++nt)
#pragma unroll
                for (int reg = 0; reg < 4; ++reg)
                    P[(mt * 16 + quad * 4 + reg) * 88 + nt * 16 + l15] = f2bf(S[mt][nt][reg]);
#pragma unroll
        for (int c2 = 0; c2 < 4; ++c2)
#pragma unroll
            for (int j = 0; j < 8; ++j)
                vt[(c2 * 8 + j) * 72 + lane] = vraw[c2][j];
        CFENCE();
        floatx4 O[4][2];
#pragma unroll
        for (int mt = 0; mt < 4; ++mt)
#pragma unroll
            for (int nt = 0; nt < 2; ++nt) O[mt][nt] = (floatx4){0.f, 0.f, 0.f, 0.f};
#pragma unroll
        for (int ks = 0; ks < 2; ++ks) {
            shortx8 pa[4], vb[2];
#pragma unroll
            for (int mt = 0; mt < 4; ++mt)
                pa[mt] = *(const shortx8*)&P[(mt * 16 + l15) * 88 + ks * 32 + quad * 8];
#pragma unroll
            for (int nt = 0; nt < 2; ++nt)
                vb[nt] = *(const shortx8*)&vt[(nt * 16 + l15) * 72 + ks * 32 + quad * 8];
#pragma unroll
            for (int mt = 0; mt < 4; ++mt)
#pragma unroll
                for (int nt = 0; nt < 2; ++nt)
                    O[mt][nt] = __builtin_amdgcn_mfma_f32_16x16x32_bf16(pa[mt], vb[nt], O[mt][nt], 0, 0, 0);
        }
#pragma unroll
        for (int mt = 0; mt < 4; ++mt)
#pragma unroll
            for (int nt = 0; nt < 2; ++nt)
#pragma unroll
                for (int reg = 0; reg < 4; ++reg) {
                    int i = mt * 16 + quad * 4 + reg;
                    int d = nt * 16 + l15;
                    aout[(size_t)(win * 64 + i) * 256 + (h << 5) + d] =
                        f2bf(O[mt][nt][reg] * rs[mt][reg]);
                }
    }
}

// ---------------- K4: output projection, A-resident ----------------
__global__ __launch_bounds__(256, 2) void oproj_gemm(const short* __restrict__ ao,
                                                     const short* __restrict__ wot,
                                                     const float* __restrict__ bo,
                                                     float* __restrict__ out) {
    __shared__ __align__(16) short As[128 * 264];
    __shared__ __align__(16) short Bs[128 * 40];
    int tid = threadIdx.x, lane = tid & 63, wid = tid >> 6;
    int quad = lane >> 4, l15 = lane & 15;
    int bm = blockIdx.x;

    {
        int r = tid >> 1, half = tid & 1;
        const short* src = ao + (size_t)(bm * 128 + r) * 256 + half * 128;
        short* dst = &As[r * 264 + half * 128];
#pragma unroll
        for (int g = 0; g < 2; ++g) {
            shortx8 v[8];
#pragma unroll
            for (int j = 0; j < 8; ++j) v[j] = *(const shortx8*)(src + g * 64 + j * 8);
#pragma unroll
            for (int j = 0; j < 8; ++j) *(shortx8*)(dst + g * 64 + j * 8) = v[j];
        }
    }

    int br = tid >> 1, bc = tid & 1;
    shortx8 pf0, pf1;
    {
        const short* p = wot + (size_t)br * 256 + bc * 16;
        pf0 = *(const shortx8*)p; pf1 = *(const shortx8*)(p + 8);
    }
    int wm = (wid & 1) * 64, wn = (wid >> 1) * 64;

    for (int t = 0; t < 2; ++t) {
        floatx4 acc[4][4];
#pragma unroll
        for (int mt = 0; mt < 4; ++mt)
#pragma unroll
            for (int nt = 0; nt < 4; ++nt) acc[mt][nt] = (floatx4){0.f, 0.f, 0.f, 0.f};
        for (int kt = 0; kt < 8; ++kt) {
            __syncthreads();
            *(shortx8*)&Bs[br * 40 + bc * 16] = pf0;
            *(shortx8*)&Bs[br * 40 + bc * 16 + 8] = pf1;
            __syncthreads();
            int nt_ = t, nkt = kt + 1;
            if (nkt == 8) { nt_ = t + 1; nkt = 0; }
            if (nt_ < 2) {
                const short* p = wot + (size_t)(nt_ * 128 + br) * 256 + nkt * 32 + bc * 16;
                pf0 = *(const shortx8*)p; pf1 = *(const shortx8*)(p + 8);
            }
            shortx8 af[4], bfr[4];
#pragma unroll
            for (int mt = 0; mt < 4; ++mt)
                af[mt] = *(const shortx8*)&As[(wm + mt * 16 + l15) * 264 + kt * 32 + quad * 8];
#pragma unroll
            for (int nt = 0; nt < 4; ++nt)
                bfr[nt] = *(const shortx8*)&Bs[(wn + nt * 16 + l15) * 40 + quad * 8];
#pragma unroll
            for (int mt = 0; mt < 4; ++mt)
#pragma unroll
                for (int nt = 0; nt < 4; ++nt)
                    acc[mt][nt] = __builtin_amdgcn_mfma_f32_16x16x32_bf16(af[mt], bfr[nt], acc[mt][nt], 0, 0, 0);
        }
        float biasv[4];
#pragma unroll
        for (int nt = 0; nt < 4; ++nt) biasv[nt] = bo[t * 128 + wn + nt * 16 + l15];
#pragma unroll
        for (int mt = 0; mt < 4; ++mt)
#pragma unroll
            for (int nt = 0; nt < 4; ++nt)
#pragma unroll
                for (int reg = 0; reg < 4; ++reg) {
                    int row = bm * 128 + wm + mt * 16 + quad * 4 + reg;
                    int col = t * 128 + wn + nt * 16 + l15;
                    out[(size_t)row2pix(row) * 256 + col] = acc[mt][nt][reg] + biasv[nt];
                }
    }
}

// ---------------- launch ----------------
extern "C" void kernel_launch(void* const* d_in, const int* in_sizes, int n_in,
                              void* d_out, int out_size, void* d_ws, size_t ws_size,
                              hipStream_t stream) {
    const float* x  = (const float*)d_in[0];
    const float* Wq = (const float*)d_in[1];
    const float* bq = (const float*)d_in[2];
    const float* Wk = (const float*)d_in[3];
    const float* bk = (const float*)d_in[4];
    const float* Wv = (const float*)d_in[5];
    const float* bv = (const float*)d_in[6];
    const float* Wo = (const float*)d_in[7];
    const float* bo = (const float*)d_in[8];
    const float* ls = (const float*)d_in[9];
    const float* w1 = (const float*)d_in[10];
    const float* b1 = (const float*)d_in[11];
    const float* w2 = (const float*)d_in[12];

    char* ws = (char*)d_ws;
    short* wqkv_t = (short*)(ws + 0);
    short* wo_t   = (short*)(ws + 393216);
    float* bias8  = (float*)(ws + 524288);
    float* scale  = (float*)(ws + 655360);
    float* b225g  = (float*)(ws + 786432);
    short* qkv    = (short*)(ws + 1048576);
    short* aout   = (short*)(ws + 101711872);
    float* out    = (float*)d_out;

    hipLaunchKernelGGL(wtrans, dim3(8, 8, 4), dim3(32, 8), 0, stream, Wq, Wk, Wv, Wo, wqkv_t, wo_t);
    hipLaunchKernelGGL(bias_mlp, dim3(225), dim3(256), 0, stream, ls, w1, b1, w2, b225g, scale);
    hipLaunchKernelGGL(bias_expand, dim3(128), dim3(256), 0, stream, b225g, bias8);
    hipLaunchKernelGGL(qkv_gemm, dim3(512), dim3(256), 0, stream, x, wqkv_t, bq, bk, bv, qkv);
    hipLaunchKernelGGL(attn_kernel, dim3(1024), dim3(256), 0, stream, qkv, bias8, scale, aout);
    hipLaunchKernelGGL(oproj_gemm, dim3(512), dim3(256), 0, stream, aout, wo_t, bo, out);
}